// Round 5
// baseline (368.694 us; speedup 1.0000x reference)
//
#include <hip/hip_runtime.h>
#include <stdint.h>

#define K_DIM 1024
#define N_DIM 1024
#define M_DIM 65536

typedef __bf16 bf16_t;
typedef __bf16 bf16x8 __attribute__((ext_vector_type(8)));
typedef float f32x4 __attribute__((ext_vector_type(4)));

#define GLOAD_LDS16(g, l) __builtin_amdgcn_global_load_lds( \
    (const __attribute__((address_space(1))) void*)(g),     \
    (__attribute__((address_space(3))) void*)(l), 16, 0, 0)

#define VMCNT(n) asm volatile("s_waitcnt vmcnt(%0)" ::"n"(n) : "memory")
#define LGKM(n) asm volatile("s_waitcnt lgkmcnt(%0)" ::"n"(n) : "memory")
#define SCHEDB() __builtin_amdgcn_sched_barrier(0)

// ---------------------------------------------------------------------------
// Quantize-dequantize to bf16 (unchanged semantics; single fused launch:
// blocks [0,512) handle w, the rest grid-stride x).
// ---------------------------------------------------------------------------
__global__ __launch_bounds__(256) void quant_dequant_kernel(
    const float* __restrict__ x, bf16_t* __restrict__ xd, long long nx,
    const float* __restrict__ w, bf16_t* __restrict__ wd, long long nw) {
  const float* in;
  bf16_t* out;
  long long i, stride, n;
  if (blockIdx.x < 512) {
    in = w; out = wd; n = nw;
    i = (long long)blockIdx.x * blockDim.x + threadIdx.x;
    stride = 512ll * blockDim.x;
  } else {
    in = x; out = xd; n = nx;
    i = (long long)(blockIdx.x - 512) * blockDim.x + threadIdx.x;
    stride = (long long)(gridDim.x - 512) * blockDim.x;
  }
  for (; i < n; i += stride) {
    long long base = i * 8;
    f32x4 v0 = *reinterpret_cast<const f32x4*>(in + base);
    f32x4 v1 = *reinterpret_cast<const f32x4*>(in + base + 4);
    float mx = 0.0f;
#pragma unroll
    for (int j = 0; j < 4; ++j) {
      mx = fmaxf(mx, fabsf(v0[j]));
      mx = fmaxf(mx, fabsf(v1[j]));
    }
    mx = fmaxf(mx, __shfl_xor(mx, 1));
    mx = fmaxf(mx, __shfl_xor(mx, 2));
    float s = fmaxf(mx / 7.5f, 1e-30f);
    bf16x8 o;
#pragma unroll
    for (int j = 0; j < 8; ++j) {
      float xv = (j < 4) ? v0[j] : v1[j - 4];
      float y = xv / s;  // fp32 div, like reference
      float m = fabsf(y);
      float h, hinv;
      if (m < 2.0f)      { h = 0.125f; hinv = 8.0f; }
      else if (m < 4.0f) { h = 0.25f;  hinv = 4.0f; }
      else               { h = 0.5f;   hinv = 2.0f; }
      float nn = m * hinv;  // exact (power-of-2 scale)
      float kf = floorf(nn);
      float fr = nn - kf;   // exact
      float up = (fr > 0.5f || (fr == 0.5f && y < 0.0f)) ? 1.0f : 0.0f;
      float q = fminf((kf + up) * h, 7.5f);
      o[j] = (bf16_t)(copysignf(q, y) * s);
    }
    *reinterpret_cast<bf16x8*>(out + base) = o;
  }
}

// ---------------------------------------------------------------------------
// bf16 GEMM C = A*B^T + bias. 256x256 tile, BK=32, 8 waves (2M x 4N).
// Round-5 restructure (post-mortem: r2/r3/r4 all serialized LDS and MFMA
// pipes at ~3300 cyc/K-tile):
//  * B (2MB, L2-resident) loaded DIRECT TO REGISTERS — no LDS staging for B.
//    Halves LDS read traffic and staging sync.
//  * A staged via global_load_lds into a 4-deep 16KB ring (64KB LDS total),
//    zero-conflict swizzle (r3/r4-verified), ONE barrier + ONE vmcnt(0) per
//    K-tile (the drained loads are a full iteration old => no stall).
//  * Both A-frags (8 ds_read_b128) and B-frags (4 global dwordx4) are
//    register-prefetched one K-tile ahead and issued BEFORE the 32-MFMA
//    burst, with only lgkm(8) between: LDS pipe (~750cyc) and L2 pipe
//    (~510cyc) run under the MFMA burst (1240cyc/CU).
//  * Unroll-4 over the ring => every LDS offset is a compile-time immediate.
// Sync proof: stage(t+2) at iter t overwrites buf[(t+2)&3]=buf[(t-2)&3],
// whose readers (pre-read of A(t-2) at iter t-3) were retired by lgkm(8) at
// iter t-2, before barrier(t). Reads of A(t+1) at iter t follow VMCNT(0)+
// barrier, after which every wave's A(t+1) stage-writes (issued iter t-1)
// have landed. MFMA(t) operands were waited by lgkm(8) (only the 8 new
// reads outstanding).
// ---------------------------------------------------------------------------
__global__ __launch_bounds__(512, 2) void mx_gemm(
    const bf16_t* __restrict__ A, const bf16_t* __restrict__ B,
    const float* __restrict__ bias, float* __restrict__ C) {
  __shared__ char lds[65536];

  const int tid = threadIdx.x;
  const int lane = tid & 63;
  const int wid = tid >> 6;
  const int wm = wid >> 2;  // 0..1  (128-row half)
  const int wn = wid & 3;   // 0..3  (64-col slice)

  // XCD-grouped mapping (verified: A fetched ~once from HBM; B L2-resident).
  const int b = blockIdx.x;
  const int xcd = b & 7;
  const int t = b >> 3;
  const int m_tile = xcd * 32 + (t >> 2);  // [0,256)
  const int n_tile = t & 3;                // [0,4)

  // A staging source (pre-swizzled, as r3/r4): row R0=tid>>2 in 128-half,
  // source col8 = (tid&3)^((tid>>3)&3).
  const int R0 = tid >> 2;
  const int c0 = ((tid & 3) ^ ((tid >> 3) & 3)) * 8;
  const bf16_t* aS0 = A + (size_t)(m_tile * 256 + R0) * K_DIM + c0;
  const bf16_t* aS1 = aS0 + (size_t)128 * K_DIM;
  const int dst16 = tid * 16;

  // A fragment ds_read offsets (zero-conflict family, lane-only swizzle).
  const int ps = (((lane >> 4) ^ ((lane >> 1) & 3)) << 4);
  const int aRd = wm * 8192 + (lane & 15) * 64 + ps;  // + i*1024 (+4096)

  // B direct-load byte offsets: row = n_tile*256 + wn*64 + j*16 + (lane&15),
  // byte = row*2048 + (lane>>4)*16 + t*64 (t*64 via advance + immediates).
  const char* Bb = (const char*)B;
  int boffj[4];
#pragma unroll
  for (int j = 0; j < 4; ++j)
    boffj[j] = (n_tile * 256 + wn * 64 + j * 16 + (lane & 15)) * 2048 +
               (lane >> 4) * 16;

  f32x4 acc[8][4];
#pragma unroll
  for (int i = 0; i < 8; ++i)
#pragma unroll
    for (int j = 0; j < 4; ++j) acc[i][j] = (f32x4)(0.0f);

  bf16x8 a[2][8], bfr[2][4];

#define BODY(Q, PAR, STG, DOB, DOA, LG)                                       \
  {                                                                           \
    VMCNT(0);                                                                 \
    __builtin_amdgcn_s_barrier();                                             \
    SCHEDB();                                                                 \
    if (STG) {                                                                \
      GLOAD_LDS16(aS0 + ((Q) + 2) * 32,                                       \
                  lds + (((Q) + 2) & 3) * 16384 + dst16);                     \
      GLOAD_LDS16(aS1 + ((Q) + 2) * 32,                                       \
                  lds + (((Q) + 2) & 3) * 16384 + 8192 + dst16);              \
    }                                                                         \
    if (DOB) {                                                                \
      _Pragma("unroll") for (int j = 0; j < 4; ++j)                           \
          bfr[(PAR) ^ 1][j] = *reinterpret_cast<const bf16x8*>(               \
              Bb + boffj[j] + ((Q) + 1) * 64);                                \
    }                                                                         \
    if (DOA) {                                                                \
      const char* sb_ = lds + (((Q) + 1) & 3) * 16384;                        \
      _Pragma("unroll") for (int i = 0; i < 4; ++i) {                         \
        a[(PAR) ^ 1][i] =                                                     \
            *reinterpret_cast<const bf16x8*>(sb_ + aRd + i * 1024);           \
        a[(PAR) ^ 1][4 + i] =                                                 \
            *reinterpret_cast<const bf16x8*>(sb_ + aRd + 4096 + i * 1024);    \
      }                                                                       \
    }                                                                         \
    SCHEDB();                                                                 \
    LGKM(LG);                                                                 \
    SCHEDB();                                                                 \
    __builtin_amdgcn_s_setprio(1);                                            \
    _Pragma("unroll") for (int i = 0; i < 8; ++i)                             \
        _Pragma("unroll") for (int j = 0; j < 4; ++j) acc[i][j] =             \
            __builtin_amdgcn_mfma_f32_16x16x32_bf16(a[PAR][i], bfr[PAR][j],   \
                                                    acc[i][j], 0, 0, 0);      \
    __builtin_amdgcn_s_setprio(0);                                            \
  }

  // Prologue: stage A(0)->buf0, A(1)->buf1; load B(0); wait stages; read A(0).
  GLOAD_LDS16(aS0, lds + dst16);
  GLOAD_LDS16(aS1, lds + 8192 + dst16);
  GLOAD_LDS16(aS0 + 32, lds + 16384 + dst16);
  GLOAD_LDS16(aS1 + 32, lds + 16384 + 8192 + dst16);
#pragma unroll
  for (int j = 0; j < 4; ++j)
    bfr[0][j] = *reinterpret_cast<const bf16x8*>(Bb + boffj[j]);
  VMCNT(4);  // retire the 4 A-stage loads; B(0) stays in flight
  __builtin_amdgcn_s_barrier();
  SCHEDB();
#pragma unroll
  for (int i = 0; i < 4; ++i) {
    a[0][i] = *reinterpret_cast<const bf16x8*>(lds + aRd + i * 1024);
    a[0][4 + i] = *reinterpret_cast<const bf16x8*>(lds + aRd + 4096 + i * 1024);
  }

  // Main loop: t = 0..27 (stage t+2 <= 29, prefetch B/A of t+1 <= 28).
  for (int p = 0; p < 7; ++p) {
    BODY(0, 0, 1, 1, 1, 8);
    BODY(1, 1, 1, 1, 1, 8);
    BODY(2, 0, 1, 1, 1, 8);
    BODY(3, 1, 1, 1, 1, 8);
    aS0 += 128;  // 4 K-tiles * 32 elems
    aS1 += 128;
#pragma unroll
    for (int j = 0; j < 4; ++j) boffj[j] += 256;
  }
  // Peeled tail: t=28 (stage 30), t=29 (stage 31), t=30, t=31.
  BODY(0, 0, 1, 1, 1, 8);
  BODY(1, 1, 1, 1, 1, 8);
  BODY(2, 0, 0, 1, 1, 8);
  BODY(3, 1, 0, 0, 0, 0);

  // Epilogue. C/D layout: col = lane&15, row = (lane>>4)*4 + reg (m89).
  const int col0 = n_tile * 256 + wn * 64 + (lane & 15);
  const int row0 = m_tile * 256 + wm * 128 + ((lane >> 4) << 2);
#pragma unroll
  for (int j = 0; j < 4; ++j) {
    float bv = bias[col0 + j * 16];
#pragma unroll
    for (int m = 0; m < 8; ++m) {
#pragma unroll
      for (int r = 0; r < 4; ++r) {
        C[(size_t)(row0 + m * 16 + r) * N_DIM + col0 + j * 16] =
            acc[m][j][r] + bv;
      }
    }
  }
#undef BODY
}

extern "C" void kernel_launch(void* const* d_in, const int* in_sizes, int n_in,
                              void* d_out, int out_size, void* d_ws,
                              size_t ws_size, hipStream_t stream) {
  const float* x = (const float*)d_in[0];     // 8*8192*1024 fp32
  const float* w = (const float*)d_in[1];     // 1024*1024 fp32
  const float* bias = (const float*)d_in[2];  // 1024 fp32
  float* out = (float*)d_out;                 // 65536*1024 fp32

  bf16_t* xd = (bf16_t*)d_ws;               // 128 MB
  bf16_t* wd = xd + (size_t)M_DIM * K_DIM;  // +2 MB

  quant_dequant_kernel<<<4608, 256, 0, stream>>>(
      x, xd, (long long)M_DIM * K_DIM / 8, w, wd,
      (long long)K_DIM * N_DIM / 8);

  mx_gemm<<<(M_DIM / 256) * (N_DIM / 256), 512, 0, stream>>>(xd, wd, bias,
                                                             out);
}

// Round 6
// 271.584 us; speedup vs baseline: 1.3576x; 1.3576x over previous
//
#include <hip/hip_runtime.h>
#include <stdint.h>

#define K_DIM 1024
#define N_DIM 1024
#define M_DIM 65536

typedef __bf16 bf16_t;
typedef __bf16 bf16x8 __attribute__((ext_vector_type(8)));
typedef float f32x4 __attribute__((ext_vector_type(4)));

#define GLOAD_LDS16(g, l) __builtin_amdgcn_global_load_lds( \
    (const __attribute__((address_space(1))) void*)(g),     \
    (__attribute__((address_space(3))) void*)(l), 16, 0, 0)

#define VMCNT(n) asm volatile("s_waitcnt vmcnt(%0)" ::"n"(n) : "memory")
#define LGKM(n) asm volatile("s_waitcnt lgkmcnt(%0)" ::"n"(n) : "memory")
#define SCHEDB() __builtin_amdgcn_sched_barrier(0)

// ---------------------------------------------------------------------------
// Quantize-dequantize to bf16 (unchanged semantics; blocks [0,512) do w,
// the rest grid-stride x).
// ---------------------------------------------------------------------------
__global__ __launch_bounds__(256) void quant_dequant_kernel(
    const float* __restrict__ x, bf16_t* __restrict__ xd, long long nx,
    const float* __restrict__ w, bf16_t* __restrict__ wd, long long nw) {
  const float* in;
  bf16_t* out;
  long long i, stride, n;
  if (blockIdx.x < 512) {
    in = w; out = wd; n = nw;
    i = (long long)blockIdx.x * blockDim.x + threadIdx.x;
    stride = 512ll * blockDim.x;
  } else {
    in = x; out = xd; n = nx;
    i = (long long)(blockIdx.x - 512) * blockDim.x + threadIdx.x;
    stride = (long long)(gridDim.x - 512) * blockDim.x;
  }
  for (; i < n; i += stride) {
    long long base = i * 8;
    f32x4 v0 = *reinterpret_cast<const f32x4*>(in + base);
    f32x4 v1 = *reinterpret_cast<const f32x4*>(in + base + 4);
    float mx = 0.0f;
#pragma unroll
    for (int j = 0; j < 4; ++j) {
      mx = fmaxf(mx, fabsf(v0[j]));
      mx = fmaxf(mx, fabsf(v1[j]));
    }
    mx = fmaxf(mx, __shfl_xor(mx, 1));
    mx = fmaxf(mx, __shfl_xor(mx, 2));
    float s = fmaxf(mx / 7.5f, 1e-30f);
    bf16x8 o;
#pragma unroll
    for (int j = 0; j < 8; ++j) {
      float xv = (j < 4) ? v0[j] : v1[j - 4];
      float y = xv / s;  // fp32 div, like reference
      float m = fabsf(y);
      float h, hinv;
      if (m < 2.0f)      { h = 0.125f; hinv = 8.0f; }
      else if (m < 4.0f) { h = 0.25f;  hinv = 4.0f; }
      else               { h = 0.5f;   hinv = 2.0f; }
      float nn = m * hinv;  // exact (power-of-2 scale)
      float kf = floorf(nn);
      float fr = nn - kf;   // exact
      float up = (fr > 0.5f || (fr == 0.5f && y < 0.0f)) ? 1.0f : 0.0f;
      float q = fminf((kf + up) * h, 7.5f);
      o[j] = (bf16_t)(copysignf(q, y) * s);
    }
    *reinterpret_cast<bf16x8*>(out + base) = o;
  }
}

// ---------------------------------------------------------------------------
// bf16 GEMM C = A*B^T + bias — faithful m201 8-phase port.
// 256x256 tile, 512 threads = 8 waves (2M x 4N), K as 32 slices of 32.
// Chunk = A[256][32] or B[256][32] bf16 = 16 KB (2 gloads/thread).
// LDS = ring of 8 chunks (128 KB). slot(A(s)) = (2s)&7, slot(B(s)) = (2s+1)&7.
// Slice s = 2 phases:
//   P0: ds_read af(m0-3) + bf(n0-3) [8 x b128] | stage {A,B}(s+2) [4 gloads]
//       | barrier | lgkm(0) | setprio(1) 16 MFMA setprio(0) | barrier
//   P1: ds_read af(m4-7) [4 x b128] | vmcnt(4)  (retires {A,B}(s+1))
//       | barrier | lgkm(0) | setprio(1) 16 MFMA setprio(0) | barrier
// Counted vmcnt once per slice, never 0 in steady state (4 loads in flight).
// Safety: reads of slice s follow every wave's vmcnt(4) at P1(s-1) + barrier;
// P0(s)'s stage overwrites chunks (s-2), whose last ds_reads retired at
// lgkm(0) of P1(s-2), two barrier-pairs earlier. Swizzle: phys 16B slot =
// logical ^ ((row>>1)&3) — measured 0 conflicts (r3/r4); staging source is
// inverse-pre-swizzled (both-sides-or-neither).
// ---------------------------------------------------------------------------
__global__ __launch_bounds__(512, 2) void mx_gemm(
    const bf16_t* __restrict__ A, const bf16_t* __restrict__ B,
    const float* __restrict__ bias, float* __restrict__ C) {
  __shared__ char lds[131072];

  const int tid = threadIdx.x;
  const int lane = tid & 63;
  const int wid = tid >> 6;
  const int wm = wid >> 2;  // 0..1  (128-row half)
  const int wn = wid & 3;   // 0..3  (64-col slice)

  // XCD-grouped mapping (verified: A ~once from HBM; B L2-resident).
  const int b = blockIdx.x;
  const int xcd = b & 7;
  const int t = b >> 3;
  const int m_tile = xcd * 32 + (t >> 2);  // [0,256)
  const int n_tile = t & 3;                // [0,4)

  // Staging source (pre-swizzled): dest row R = tid>>2 (load0) / +128
  // (load1); source col8 = (tid&3) ^ ((tid>>3)&3)  (R>>1 parity; 128 == 0
  // mod 4 so load1 uses the same xor).
  const int R0 = tid >> 2;
  const int c0 = ((tid & 3) ^ ((tid >> 3) & 3)) * 8;
  const bf16_t* aS0 = A + (size_t)(m_tile * 256 + R0) * K_DIM + c0;
  const bf16_t* aS1 = aS0 + (size_t)128 * K_DIM;
  const bf16_t* bS0 = B + (size_t)(n_tile * 256 + R0) * K_DIM + c0;
  const bf16_t* bS1 = bS0 + (size_t)128 * K_DIM;
  const int dst16 = tid * 16;

#define STG_A(KOFF, SLOT)                           \
  {                                                 \
    char* d_ = lds + (SLOT) * 16384 + dst16;        \
    GLOAD_LDS16(aS0 + (KOFF), d_);                  \
    GLOAD_LDS16(aS1 + (KOFF), d_ + 8192);           \
  }
#define STG_B(KOFF, SLOT)                           \
  {                                                 \
    char* d_ = lds + (SLOT) * 16384 + dst16;        \
    GLOAD_LDS16(bS0 + (KOFF), d_);                  \
    GLOAD_LDS16(bS1 + (KOFF), d_ + 8192);           \
  }

  // Fragment ds_read offsets (zero-conflict family, lane-only swizzle).
  const int swz = (((lane >> 4) ^ ((lane >> 1) & 3)) << 4);
  const int aRd = (wm * 128 + (lane & 15)) * 64 + swz;  // + i*1024, i=0..7
  const int bRd = (wn * 64 + (lane & 15)) * 64 + swz;   // + j*1024, j=0..3

  f32x4 acc[8][4];
#pragma unroll
  for (int i = 0; i < 8; ++i)
#pragma unroll
    for (int j = 0; j < 4; ++j) acc[i][j] = (f32x4)(0.0f);

#define SLICE(SQ, KOFF, DO_STG, DO_V, VN)                                    \
  {                                                                          \
    const char* cA_ = lds + (((2 * (SQ)) & 7) * 16384);                      \
    const char* cB_ = lds + (((2 * (SQ) + 1) & 7) * 16384);                  \
    bf16x8 af[4], bf[4];                                                     \
    /* ---- P0 ---- */                                                       \
    _Pragma("unroll") for (int i = 0; i < 4; ++i) af[i] =                    \
        *reinterpret_cast<const bf16x8*>(cA_ + aRd + i * 1024);              \
    _Pragma("unroll") for (int j = 0; j < 4; ++j) bf[j] =                    \
        *reinterpret_cast<const bf16x8*>(cB_ + bRd + j * 1024);              \
    if (DO_STG) {                                                            \
      STG_A((KOFF) + 64, ((2 * (SQ) + 4) & 7));                              \
      STG_B((KOFF) + 64, ((2 * (SQ) + 5) & 7));                              \
    }                                                                        \
    SCHEDB();                                                                \
    __builtin_amdgcn_s_barrier();                                            \
    LGKM(0);                                                                 \
    SCHEDB();                                                                \
    __builtin_amdgcn_s_setprio(1);                                           \
    _Pragma("unroll") for (int i = 0; i < 4; ++i)                            \
        _Pragma("unroll") for (int j = 0; j < 4; ++j) acc[i][j] =            \
            __builtin_amdgcn_mfma_f32_16x16x32_bf16(af[i], bf[j],            \
                                                    acc[i][j], 0, 0, 0);     \
    __builtin_amdgcn_s_setprio(0);                                           \
    SCHEDB();                                                                \
    __builtin_amdgcn_s_barrier();                                            \
    /* ---- P1 ---- */                                                       \
    _Pragma("unroll") for (int i = 0; i < 4; ++i) af[i] =                    \
        *reinterpret_cast<const bf16x8*>(cA_ + aRd + 4096 + i * 1024);       \
    if (DO_V) { VMCNT(VN); }                                                 \
    SCHEDB();                                                                \
    __builtin_amdgcn_s_barrier();                                            \
    LGKM(0);                                                                 \
    SCHEDB();                                                                \
    __builtin_amdgcn_s_setprio(1);                                           \
    _Pragma("unroll") for (int i = 0; i < 4; ++i)                            \
        _Pragma("unroll") for (int j = 0; j < 4; ++j) acc[4 + i][j] =        \
            __builtin_amdgcn_mfma_f32_16x16x32_bf16(af[i], bf[j],            \
                                                    acc[4 + i][j], 0, 0, 0); \
    __builtin_amdgcn_s_setprio(0);                                           \
    SCHEDB();                                                                \
    __builtin_amdgcn_s_barrier();                                            \
  }

  // Prologue: stage slices 0,1 (slots 0..3); ensure slice 0 landed.
  STG_A(0, 0);
  STG_B(0, 1);
  STG_A(32, 2);
  STG_B(32, 3);
  VMCNT(4);  // retire {A,B}(0); {A,B}(1) stays in flight
  __builtin_amdgcn_s_barrier();

  // Slices 0..27 (each stages slice s+2; vmcnt(4) retires slice s+1).
  for (int g = 0; g < 7; ++g) {
    SLICE(0, 0, 1, 1, 4);
    SLICE(1, 32, 1, 1, 4);
    SLICE(2, 64, 1, 1, 4);
    SLICE(3, 96, 1, 1, 4);
    aS0 += 128;
    aS1 += 128;
    bS0 += 128;
    bS1 += 128;
  }
  // Tail: s=28 (stage 30), s=29 (stage 31), s=30 (vmcnt 0 retires 31), s=31.
  SLICE(0, 0, 1, 1, 4);
  SLICE(1, 32, 1, 1, 4);
  SLICE(2, 64, 0, 1, 0);
  SLICE(3, 96, 0, 0, 0);

  // Epilogue. C/D layout: col = lane&15, row = (lane>>4)*4 + reg (m89).
  const int col0 = n_tile * 256 + wn * 64 + (lane & 15);
  const int row0 = m_tile * 256 + wm * 128 + ((lane >> 4) << 2);
#pragma unroll
  for (int j = 0; j < 4; ++j) {
    float bv = bias[col0 + j * 16];
#pragma unroll
    for (int m = 0; m < 8; ++m) {
#pragma unroll
      for (int r = 0; r < 4; ++r) {
        C[(size_t)(row0 + m * 16 + r) * N_DIM + col0 + j * 16] =
            acc[m][j][r] + bv;
      }
    }
  }
#undef STG_A
#undef STG_B
#undef SLICE
}

extern "C" void kernel_launch(void* const* d_in, const int* in_sizes, int n_in,
                              void* d_out, int out_size, void* d_ws,
                              size_t ws_size, hipStream_t stream) {
  const float* x = (const float*)d_in[0];     // 8*8192*1024 fp32
  const float* w = (const float*)d_in[1];     // 1024*1024 fp32
  const float* bias = (const float*)d_in[2];  // 1024 fp32
  float* out = (float*)d_out;                 // 65536*1024 fp32

  bf16_t* xd = (bf16_t*)d_ws;               // 128 MB
  bf16_t* wd = xd + (size_t)M_DIM * K_DIM;  // +2 MB

  quant_dequant_kernel<<<4608, 256, 0, stream>>>(
      x, xd, (long long)M_DIM * K_DIM / 8, w, wd,
      (long long)K_DIM * N_DIM / 8);

  mx_gemm<<<(M_DIM / 256) * (N_DIM / 256), 512, 0, stream>>>(xd, wd, bias,
                                                             out);
}